// Round 7
// baseline (316.703 us; speedup 1.0000x reference)
//
#include <hip/hip_runtime.h>
#include <hip/hip_bf16.h>

#define BN_EPS 1e-5f

typedef short s8v __attribute__((ext_vector_type(8)));
typedef float f4v __attribute__((ext_vector_type(4)));
typedef unsigned short u16x8 __attribute__((ext_vector_type(8)));

__device__ __forceinline__ float bu2f(unsigned short u) {
    union { unsigned int i; float f; } c; c.i = ((unsigned int)u) << 16; return c.f;
}
__device__ __forceinline__ unsigned short f2bu(float f) {
    union { float f; unsigned int i; } c; c.f = f;
    unsigned int i = c.i;
    i += 0x7FFFu + ((i >> 16) & 1u);   // RNE
    return (unsigned short)(i >> 16);
}
__device__ __forceinline__ float gelu_exact(float x) {
    return 0.5f * x * (1.0f + erff(x * 0.70710678118654752f));
}
__device__ __forceinline__ float ldin(const void* p, long i, bool f32) {
    return f32 ? ((const float*)p)[i] : bu2f(((const unsigned short*)p)[i]);
}
__device__ __forceinline__ s8v ldfrag(const unsigned short* p) {
    return *reinterpret_cast<const s8v*>(p);
}
// async 16B global->LDS DMA (lane i lands at lds + i*16; lds must be wave-uniform)
__device__ __forceinline__ void gld16(const void* g, void* l) {
    __builtin_amdgcn_global_load_lds(
        (const __attribute__((address_space(1))) unsigned int*)g,
        (__attribute__((address_space(3))) unsigned int*)l, 16, 0, 0);
}
// swizzled fragment read from unpadded 32-short rows: slot = quad ^ ((row>>1)&3)
__device__ __forceinline__ s8v ldsw32(const unsigned short* T, int row, int quad) {
    return *reinterpret_cast<const s8v*>(T + row * 32 + ((quad ^ ((row >> 1) & 3)) << 3));
}
// swizzled read from unpadded 64-short rows (8 chunks): slot = chunk ^ (row&7)
__device__ __forceinline__ s8v ldsw64(const unsigned short* T, int row, int chunk) {
    return *reinterpret_cast<const s8v*>(T + row * 64 + ((chunk ^ (row & 7)) << 3));
}
__device__ __forceinline__ int detect_f32(const unsigned short* xu) {
    int insane = 0;
    for (int i = 0; i < 128; ++i) {
        unsigned int e = (xu[i] >> 7) & 0xFFu;
        if (e == 255u || (e != 0u && (e < 96u || e > 159u))) ++insane;
    }
    return (insane >= 16) ? 1 : 0;
}

// ------------- fused prep: dtype flag + weight conv + x transposes ----------
// kv weights are gathered h-major: wKVk[h*32+d] and wKVv[h*128+v].
// blocks [0,960): weights (8 el/thread); [960,3008): xT; [3008,3520): xqT
__global__ __launch_bounds__(256)
void prep_kernel(const void* __restrict__ x,
                 const void* __restrict__ w0, const void* __restrict__ w1,
                 const void* __restrict__ w2, const void* __restrict__ w3,
                 const void* __restrict__ w4,
                 unsigned short* __restrict__ wdst,
                 unsigned short* __restrict__ xT,
                 unsigned short* __restrict__ xqT,
                 int* __restrict__ dtf)
{
    __shared__ int sflag;
    __shared__ unsigned short T[64][66];
    const int tid = threadIdx.x;
    const int bid = blockIdx.x;
    if (tid == 0) {
        int fl = detect_f32((const unsigned short*)x);
        sflag = fl;
        if (bid == 0) *dtf = fl;
    }
    __syncthreads();
    const bool f = (sflag != 0);

    if (bid < 960) {
        long idx = (long)bid * 2048 + tid * 8;
        const void* s; long off;
        if (idx < 65536L) {                    // wKVk: row rk -> kv_w row
            long rk = idx >> 8;
            s = w0; off = ((rk >> 5) * 160 + (rk & 31)) * 256 + (idx & 255);
        } else if (idx < 327680L) {            // wKVv: row rv -> kv_w row
            long rv = (idx - 65536L) >> 8;
            s = w0; off = ((rv >> 7) * 160 + 32 + (rv & 127)) * 256 + (idx & 255);
        }
        else if (idx <  393216L) { s = w1; off = idx - 327680L; }
        else if (idx <  917504L) { s = w2; off = idx - 393216L; }
        else if (idx < 1441792L) { s = w3; off = idx - 917504L; }
        else                     { s = w4; off = idx - 1441792L; }
        u16x8 pk;
        if (f) {
            float4 a = *((const float4*)((const float*)s + off));
            float4 b = *((const float4*)((const float*)s + off + 4));
            pk[0]=f2bu(a.x); pk[1]=f2bu(a.y); pk[2]=f2bu(a.z); pk[3]=f2bu(a.w);
            pk[4]=f2bu(b.x); pk[5]=f2bu(b.y); pk[6]=f2bu(b.z); pk[7]=f2bu(b.w);
        } else {
            pk = *((const u16x8*)((const unsigned short*)s + off));
        }
        *reinterpret_cast<u16x8*>(wdst + idx) = pk;
        return;
    }
    // transpose branches: src x [b][256][1024] -> dst [b][ND][256]
    int b, c0, n0, ND; bool SUBS;
    if (bid < 3008) { int t = bid - 960;  b = t >> 6; int r = t & 63;
                      c0 = (r >> 4) * 64; n0 = (r & 15) * 64; ND = 1024; SUBS = false; }
    else            { int t = bid - 3008; b = t >> 4; int r = t & 15;
                      c0 = (r >> 2) * 64; n0 = (r & 3) * 64;  ND = 256;  SUBS = true; }
    unsigned short* dst = SUBS ? xqT : xT;
    {
        int nn = tid & 63, cq = tid >> 6;
        int n = n0 + nn;
        int sc = SUBS ? ((n >> 4) * 64 + (n & 15) * 2) : n;
        long base = ((long)b * 256 + c0 + cq * 16) * 1024 + sc;
        #pragma unroll
        for (int i = 0; i < 16; ++i)
            T[nn][cq * 16 + i] = f2bu(ldin(x, base + (long)i * 1024, f));
    }
    __syncthreads();
    {
        int cc = tid & 63, nq = tid >> 6;
        #pragma unroll
        for (int i = 0; i < 16; ++i) {
            int nn = nq * 16 + i;
            dst[((long)b * ND + n0 + nn) * 256 + c0 + cc] = T[nn][cc];
        }
    }
}

// ---------------- MFMA GEMM: C = BN(W @ X), X given transposed --------------
// A [M][K] bf16, B [b][N][K] bf16. Tile 64 x 128, BK=64, async LDS staging.
// OUT_MODE 0: transposed bf16 out0[b][N][M]       (LDS-bounced, coalesced)
// OUT_MODE 2: normal external out0 [b'][M][256], b'=n>>8 (N-folded batch)
// OUT_MODE 3: head-split transposed out0 [b*8+h][N][32]  (q / kvK)
// REMAPK: BN params indexed at (m>>5)*160+(m&31) (kvK gathered weights)
template<int OUT_MODE, bool DO_GELU, bool PRESCALE, bool REMAPK>
__global__ __launch_bounds__(256, 4)
void mfma_gemm(const unsigned short* __restrict__ A,
               const unsigned short* __restrict__ B,
               const void* __restrict__ gg, const void* __restrict__ bb,
               const void* __restrict__ mmu, const void* __restrict__ vv,
               void* __restrict__ out0,
               int M, int K, int N, const int* __restrict__ dtflag)
{
    __shared__ union {
        struct { unsigned short As[64 * 64]; unsigned short Bs[128 * 64]; } s;
        unsigned short tile[128 * 68];   // [n][m] padded, OUT_MODE 0/3 bounce
    } u;
    __shared__ float sS[64], sO[64];

    const bool wf = (*dtflag != 0);
    const int tid = threadIdx.x;
    const int lane = tid & 63;
    const int wave = tid >> 6;
    const int quad = lane >> 4;
    const int l15  = lane & 15;
    const int wn2 = wave * 32;
    const int b  = blockIdx.z;
    const int bm = blockIdx.y * 64;
    const int bn = blockIdx.x * 128;

    if (tid < 64) {
        int m = bm + tid;
        int mo = REMAPK ? ((m >> 5) * 160 + (m & 31)) : m;
        float g  = ldin(gg,  mo, wf), be = ldin(bb,  mo, wf);
        float mu = ldin(mmu, mo, wf), va = ldin(vv,  mo, wf);
        float s = g * rsqrtf(va + BN_EPS);
        float o = be - mu * s;
        if (PRESCALE) { s *= 0.17677669529663687f; o *= 0.17677669529663687f; }
        sS[tid] = s; sO[tid] = o;
    }

    const unsigned short* Bb = B + (long)b * N * K;

    f4v acc[4][2];
    #pragma unroll
    for (int i = 0; i < 4; ++i)
        #pragma unroll
        for (int j = 0; j < 2; ++j) acc[i][j] = (f4v){0.f, 0.f, 0.f, 0.f};

    const int lr8 = lane >> 3;   // row within 8-row stage group
    const int lc8 = lane & 7;    // chunk slot 0..7

    for (int k0 = 0; k0 < K; k0 += 64) {
        #pragma unroll
        for (int j = 0; j < 2; ++j) {
            int base = wave * 16 + j * 8;
            int r = base + lr8;
            gld16(A + (long)(bm + r) * K + k0 + ((lc8 ^ (r & 7)) << 3),
                  u.s.As + base * 64);
        }
        #pragma unroll
        for (int j = 0; j < 4; ++j) {
            int base = wave * 32 + j * 8;
            int r = base + lr8;
            gld16(Bb + (long)(bn + r) * K + k0 + ((lc8 ^ (r & 7)) << 3),
                  u.s.Bs + base * 64);
        }
        __syncthreads();

        #pragma unroll
        for (int sk = 0; sk < 2; ++sk) {
            s8v af[4], bfr[2];
            #pragma unroll
            for (int i = 0; i < 4; ++i)
                af[i]  = ldsw64(u.s.As, i * 16 + l15, sk * 4 + quad);
            #pragma unroll
            for (int j = 0; j < 2; ++j)
                bfr[j] = ldsw64(u.s.Bs, wn2 + j * 16 + l15, sk * 4 + quad);
            #pragma unroll
            for (int i = 0; i < 4; ++i)
                #pragma unroll
                for (int j = 0; j < 2; ++j)
                    acc[i][j] = __builtin_amdgcn_mfma_f32_16x16x32_bf16(
                        af[i], bfr[j], acc[i][j], 0, 0, 0);
        }
        __syncthreads();
    }

    if (OUT_MODE == 0 || OUT_MODE == 3) {
        // bounce acc -> LDS tile [n][m] (b64 writes), then coalesced rows out
        #pragma unroll
        for (int j = 0; j < 2; ++j) {
            int n = wn2 + j * 16 + l15;
            #pragma unroll
            for (int i = 0; i < 4; ++i) {
                int mcol = i * 16 + quad * 4;
                ushort4 pk;
                float v0 = acc[i][j][0] * sS[mcol + 0] + sO[mcol + 0];
                float v1 = acc[i][j][1] * sS[mcol + 1] + sO[mcol + 1];
                float v2 = acc[i][j][2] * sS[mcol + 2] + sO[mcol + 2];
                float v3 = acc[i][j][3] * sS[mcol + 3] + sO[mcol + 3];
                if (DO_GELU) {
                    v0 = gelu_exact(v0); v1 = gelu_exact(v1);
                    v2 = gelu_exact(v2); v3 = gelu_exact(v3);
                }
                pk.x = f2bu(v0); pk.y = f2bu(v1); pk.z = f2bu(v2); pk.w = f2bu(v3);
                *reinterpret_cast<ushort4*>(&u.tile[n * 68 + mcol]) = pk;
            }
        }
        __syncthreads();
        #pragma unroll
        for (int p = 0; p < 4; ++p) {
            int n = p * 32 + (tid >> 3), c = tid & 7;
            u16x8 val = *reinterpret_cast<const u16x8*>(&u.tile[n * 68 + c * 8]);
            if (OUT_MODE == 0) {
                *reinterpret_cast<u16x8*>(
                    (unsigned short*)out0 + ((long)b * N + bn + n) * M + bm + c * 8) = val;
            } else {
                int m = bm + c * 8, h = m >> 5;
                *reinterpret_cast<u16x8*>(
                    (unsigned short*)out0 + (((long)b * 8 + h) * N + bn + n) * 32 + (m & 31)) = val;
            }
        }
    } else {  // OUT_MODE 2: normal external [b'][M][256]
        #pragma unroll
        for (int i = 0; i < 4; ++i) {
            int m0l = i * 16 + quad * 4;
            int m0  = bm + m0l;
            float s0 = sS[m0l + 0], o0 = sO[m0l + 0];
            float s1 = sS[m0l + 1], o1 = sO[m0l + 1];
            float s2 = sS[m0l + 2], o2 = sO[m0l + 2];
            float s3 = sS[m0l + 3], o3 = sO[m0l + 3];
            #pragma unroll
            for (int j = 0; j < 2; ++j) {
                int n = bn + wn2 + j * 16 + l15;
                float v0 = acc[i][j][0] * s0 + o0;
                float v1 = acc[i][j][1] * s1 + o1;
                float v2 = acc[i][j][2] * s2 + o2;
                float v3 = acc[i][j][3] * s3 + o3;
                int b2 = n >> 8, nl = n & 255;
                long ob = ((long)b2 * M + m0) * 256 + nl;
                if (wf) {
                    ((float*)out0)[ob + 0L * 256] = v0;
                    ((float*)out0)[ob + 1L * 256] = v1;
                    ((float*)out0)[ob + 2L * 256] = v2;
                    ((float*)out0)[ob + 3L * 256] = v3;
                } else {
                    ((unsigned short*)out0)[ob + 0L * 256] = f2bu(v0);
                    ((unsigned short*)out0)[ob + 1L * 256] = f2bu(v1);
                    ((unsigned short*)out0)[ob + 2L * 256] = f2bu(v2);
                    ((unsigned short*)out0)[ob + 3L * 256] = f2bu(v3);
                }
            }
        }
    }
}

// ---------------- kvV GEMM, swapped operands for coalesced [v][keys] --------
// D[key][vch] = sum_c xT[b][key][c] * wV[vch][c]; BN per vch; output
// kvV[b*8+h][v][1024 keys] stored as 128B-contiguous key-rows via LDS bounce.
__global__ __launch_bounds__(256, 4)
void kvv_gemm(const unsigned short* __restrict__ xT,
              const unsigned short* __restrict__ wV,
              const void* __restrict__ gg, const void* __restrict__ bb,
              const void* __restrict__ mmu, const void* __restrict__ vv,
              unsigned short* __restrict__ kvV, const int* __restrict__ dtflag)
{
    __shared__ union {
        struct { unsigned short As[128 * 64]; unsigned short Bs[128 * 64]; } s;
        unsigned short VT[128 * 132];   // [vch][key] padded bounce tile
    } u;
    __shared__ float sS[128], sO[128];

    const bool wf = (*dtflag != 0);
    const int tid = threadIdx.x;
    const int lane = tid & 63;
    const int wave = tid >> 6;
    const int quad = lane >> 4;
    const int l15  = lane & 15;
    const int wm2 = (wave >> 1) * 64;   // key half
    const int wn2 = (wave & 1) * 64;    // vch half
    const int b  = blockIdx.z;
    const int bv = blockIdx.x * 128;    // vch tile (one head: 128-aligned)
    const int bk = blockIdx.y * 128;    // key tile

    if (tid < 128) {
        int vg = bv + tid;
        int mo = (vg >> 7) * 160 + 32 + (vg & 127);
        float g  = ldin(gg,  mo, wf), be = ldin(bb,  mo, wf);
        float mu = ldin(mmu, mo, wf), va = ldin(vv,  mo, wf);
        float s = g * rsqrtf(va + BN_EPS);
        sS[tid] = s; sO[tid] = be - mu * s;
    }

    const unsigned short* Xb = xT + (long)b * 1024 * 256;

    f4v acc[4][4];
    #pragma unroll
    for (int i = 0; i < 4; ++i)
        #pragma unroll
        for (int j = 0; j < 4; ++j) acc[i][j] = (f4v){0.f, 0.f, 0.f, 0.f};

    const int lr8 = lane >> 3;
    const int lc8 = lane & 7;

    for (int k0 = 0; k0 < 256; k0 += 64) {
        #pragma unroll
        for (int j = 0; j < 4; ++j) {
            int base = wave * 32 + j * 8;
            int r = base + lr8;
            gld16(Xb + (long)(bk + r) * 256 + k0 + ((lc8 ^ (r & 7)) << 3),
                  u.s.As + base * 64);
            gld16(wV + (long)(bv + r) * 256 + k0 + ((lc8 ^ (r & 7)) << 3),
                  u.s.Bs + base * 64);
        }
        __syncthreads();

        #pragma unroll
        for (int sk = 0; sk < 2; ++sk) {
            s8v af[4], bfr[4];
            #pragma unroll
            for (int i = 0; i < 4; ++i)
                af[i]  = ldsw64(u.s.As, wm2 + i * 16 + l15, sk * 4 + quad);
            #pragma unroll
            for (int j = 0; j < 4; ++j)
                bfr[j] = ldsw64(u.s.Bs, wn2 + j * 16 + l15, sk * 4 + quad);
            #pragma unroll
            for (int i = 0; i < 4; ++i)
                #pragma unroll
                for (int j = 0; j < 4; ++j)
                    acc[i][j] = __builtin_amdgcn_mfma_f32_16x16x32_bf16(
                        af[i], bfr[j], acc[i][j], 0, 0, 0);
        }
        __syncthreads();
    }

    // bounce: lane holds 4 consecutive keys for one vch -> b64 LDS writes
    #pragma unroll
    for (int j = 0; j < 4; ++j) {
        int vloc = wn2 + j * 16 + l15;
        float s = sS[vloc], o = sO[vloc];
        #pragma unroll
        for (int i = 0; i < 4; ++i) {
            int kcol = wm2 + i * 16 + quad * 4;
            ushort4 pk;
            pk.x = f2bu(acc[i][j][0] * s + o);
            pk.y = f2bu(acc[i][j][1] * s + o);
            pk.z = f2bu(acc[i][j][2] * s + o);
            pk.w = f2bu(acc[i][j][3] * s + o);
            *reinterpret_cast<ushort4*>(&u.VT[vloc * 132 + kcol]) = pk;
        }
    }
    __syncthreads();
    // coalesced store: 128B-contiguous key-runs per vch row
    const int h = bv >> 7;
    #pragma unroll
    for (int p = 0; p < 8; ++p) {
        int vloc = p * 16 + (tid >> 4), c = tid & 15;
        u16x8 val = *reinterpret_cast<const u16x8*>(&u.VT[vloc * 132 + c * 8]);
        *reinterpret_cast<u16x8*>(
            kvV + (((long)b * 8 + h) * 128 + (bv & 127) + vloc) * 1024 + bk + c * 8) = val;
    }
}

// ------- MFMA flash attention + GELU, static-max softmax (unchanged) --------
__global__ __launch_bounds__(512, 4)
void attn_mfma(const unsigned short* __restrict__ kvK,
               const unsigned short* __restrict__ kvV,
               const unsigned short* __restrict__ qh,
               unsigned short* __restrict__ goT)
{
    __shared__ unsigned short Ks[64 * 32];
    __shared__ unsigned short Vs[128 * 64];
    __shared__ unsigned short Ps[128][72];
    __shared__ float redS[128];

    const int tid = threadIdx.x;
    const int lane = tid & 63;
    const int wave = tid >> 6;
    const int quad = lane >> 4;
    const int l15  = lane & 15;
    const int h    = blockIdx.x;
    const int b    = blockIdx.y;
    const int q0   = blockIdx.z * 128;
    const int wq   = wave * 16;

    const unsigned short* Qb = qh  + (long)(b * 8 + h) * 256 * 32;
    const unsigned short* Kb = kvK + (long)(b * 8 + h) * 1024 * 32;
    const unsigned short* Vb = kvV + (long)(b * 8 + h) * 128 * 1024;

    s8v qf = ldfrag(Qb + (long)(q0 + wq + l15) * 32 + quad * 8);

    f4v o[8];
    #pragma unroll
    for (int i = 0; i < 8; ++i) o[i] = (f4v){0.f, 0.f, 0.f, 0.f};
    float rs[4] = {0.f, 0.f, 0.f, 0.f};

    for (int n0 = 0; n0 < 1024; n0 += 64) {
        if (wave < 4) {
            int r = wave * 16 + (lane >> 2);
            int c = (lane & 3) ^ ((r >> 1) & 3);
            gld16(Kb + (long)(n0 + r) * 32 + (c << 3), Ks + wave * 16 * 32);
        }
        {
            int rb = wave * 16;
            int r0 = rb + (lane >> 3), r1 = r0 + 8;
            int s  = lane & 7;
            gld16(Vb + (long)r0 * 1024 + n0 + ((s ^ (r0 & 7)) << 3), Vs + rb * 64);
            gld16(Vb + (long)r1 * 1024 + n0 + ((s ^ (r1 & 7)) << 3), Vs + (rb + 8) * 64);
        }
        __syncthreads();

        #pragma unroll
        for (int j = 0; j < 4; ++j) {
            s8v kf = ldsw32(Ks, j * 16 + l15, quad);
            f4v z = (f4v){0.f, 0.f, 0.f, 0.f};
            f4v sa = __builtin_amdgcn_mfma_f32_16x16x32_bf16(qf, kf, z, 0, 0, 0);
            #pragma unroll
            for (int r = 0; r < 4; ++r) {
                float p = __expf(fminf(sa[r], 30.f));
                rs[r] += p;
                Ps[wq + quad * 4 + r][j * 16 + l15] = f2bu(p);
            }
        }
        #pragma unroll
        for (int ks = 0; ks < 2; ++ks) {
            s8v pf = ldfrag(&Ps[wq + l15][ks * 32 + quad * 8]);
            #pragma unroll
            for (int i = 0; i < 8; ++i) {
                s8v vf = ldsw64(Vs, i * 16 + l15, ks * 4 + quad);
                o[i] = __builtin_amdgcn_mfma_f32_16x16x32_bf16(vf, pf, o[i], 0, 0, 0);
            }
        }
        __syncthreads();
    }

    #pragma unroll
    for (int r = 0; r < 4; ++r) {
        float s = rs[r];
        s += __shfl_xor(s, 1);
        s += __shfl_xor(s, 2);
        s += __shfl_xor(s, 4);
        s += __shfl_xor(s, 8);
        if (l15 == 0) redS[wq + quad * 4 + r] = s;
    }
    float linv = 1.0f / redS[wq + l15];
    int q = q0 + wq + l15;
    #pragma unroll
    for (int i = 0; i < 8; ++i) {
        ushort4 pk;
        pk.x = f2bu(gelu_exact(o[i][0] * linv));
        pk.y = f2bu(gelu_exact(o[i][1] * linv));
        pk.z = f2bu(gelu_exact(o[i][2] * linv));
        pk.w = f2bu(gelu_exact(o[i][3] * linv));
        *reinterpret_cast<ushort4*>(
            goT + ((long)b * 256 + q) * 1024 + h * 128 + i * 16 + quad * 4) = pk;
    }
}

// ---------------------------------------------------------------------------
extern "C" void kernel_launch(void* const* d_in, const int* in_sizes, int n_in,
                              void* d_out, int out_size, void* d_ws, size_t ws_size,
                              hipStream_t stream)
{
    const void* x     = d_in[0];
    const void* kv_w  = d_in[1];
    const void* kv_g  = d_in[2];  const void* kv_b  = d_in[3];
    const void* kv_m  = d_in[4];  const void* kv_v  = d_in[5];
    const void* q_w   = d_in[6];
    const void* q_g   = d_in[7];  const void* q_b   = d_in[8];
    const void* q_m   = d_in[9];  const void* q_v   = d_in[10];
    const void* mg_w  = d_in[11];
    const void* mg_g  = d_in[12]; const void* mg_b  = d_in[13];
    const void* mg_m  = d_in[14]; const void* mg_v  = d_in[15];
    const void* fc1_w = d_in[16];
    const void* bn1_g = d_in[17]; const void* bn1_b = d_in[18];
    const void* bn1_m = d_in[19]; const void* bn1_v = d_in[20];
    const void* fc2_w = d_in[21];
    const void* bn2_g = d_in[22]; const void* bn2_b = d_in[23];
    const void* bn2_m = d_in[24]; const void* bn2_v = d_in[25];

    // ws layout (bf16 elements)
    unsigned short* ws  = (unsigned short*)d_ws;
    int*            dtf = (int*)d_ws;
    unsigned short* wsW  = ws + 8;               // 1,966,080
    unsigned short* wKVk = wsW;                  //    65,536 (h-major K rows)
    unsigned short* wKVv = wsW + 65536L;         //   262,144 (h-major V rows)
    unsigned short* wQ   = wsW + 327680L;
    unsigned short* wMG  = wsW + 393216L;
    unsigned short* wFC1 = wsW + 917504L;
    unsigned short* wFC2 = wsW + 1441792L;
    unsigned short* xT   = ws + 1966088L;        // 8,388,608 (aliased by goT)
    unsigned short* goT  = xT;
    unsigned short* xqT  = ws + 10354696L;       // 2,097,152
    unsigned short* qhb  = ws + 12451848L;       // 2,097,152
    unsigned short* kvK  = ws + 14549000L;       // 8,388,608
    unsigned short* kvV  = ws + 22937608L;       // 33,554,432 (aliased by y1/y2)
    unsigned short* y1T  = kvV;                  // [8192][512]
    unsigned short* y2T  = kvV + 4194304L;       // [8192][1024]

    dim3 blk(256, 1, 1);

    // fused prep: dtype detect + weight conv/gather + xT + xqT
    prep_kernel<<<3520, blk, 0, stream>>>(
        x, kv_w, q_w, mg_w, fc1_w, fc2_w, wsW, xT, xqT, dtf);

    // q proj + BN (scale folded) -> qh [b*8+h][256][32]
    mfma_gemm<3, false, true, false><<<dim3(2, 4, 32), blk, 0, stream>>>(
        wQ, xqT, q_g, q_b, q_m, q_v, qhb, 256, 256, 256, dtf);

    // K proj + BN -> kvK [b*8+h][1024][32]
    mfma_gemm<3, false, false, true><<<dim3(8, 4, 32), blk, 0, stream>>>(
        wKVk, xT, kv_g, kv_b, kv_m, kv_v, kvK, 256, 256, 1024, dtf);

    // V proj + BN (swapped operands, coalesced) -> kvV [b*8+h][128][1024]
    kvv_gemm<<<dim3(8, 8, 32), blk, 0, stream>>>(
        xT, wKVv, kv_g, kv_b, kv_m, kv_v, kvV, dtf);

    // flash attention + GELU -> goT [b][256][1024]
    attn_mfma<<<dim3(8, 32, 2), dim3(512, 1, 1), 0, stream>>>(kvK, kvV, qhb, goT);

    // merge proj + BN -> y1T [8192][512]
    mfma_gemm<0, false, false, false><<<dim3(64, 8, 1), blk, 0, stream>>>(
        wMG, goT, mg_g, mg_b, mg_m, mg_v, y1T, 512, 1024, 8192, dtf);

    // fc1 + BN + GELU -> y2T [8192][1024]
    mfma_gemm<0, true, false, false><<<dim3(64, 16, 1), blk, 0, stream>>>(
        wFC1, y1T, bn1_g, bn1_b, bn1_m, bn1_v, y2T, 1024, 512, 8192, dtf);

    // fc2 + BN -> d_out [b][512][16][16] (external dtype)
    mfma_gemm<2, false, false, false><<<dim3(64, 8, 1), blk, 0, stream>>>(
        wFC2, y2T, bn2_g, bn2_b, bn2_m, bn2_v, d_out, 512, 1024, 8192, dtf);
}